// Round 1
// baseline (329.071 us; speedup 1.0000x reference)
//
#include <hip/hip_runtime.h>
#include <hip/hip_bf16.h>
#include <stdint.h>

#define D_DIM 128
#define L_REL 32

typedef __attribute__((ext_vector_type(8))) short short8;   // 8 bf16 = 4 VGPR
typedef __attribute__((ext_vector_type(4))) float f32x4;    // MFMA accumulator

__device__ __forceinline__ unsigned short f2bf(float f) {
    union { float f; unsigned u; } v; v.f = f;
    unsigned r = v.u + 0x7FFFu + ((v.u >> 16) & 1u);   // round-to-nearest-even
    return (unsigned short)(r >> 16);
}

// Load W fragments for this wave's 32 output columns into registers.
// b-operand fragment: lane holds W[k][c] for c = tile*16 + (lane&15),
// k = kk*32 + (lane>>4)*8 + j  (j contiguous) -- i.e. rows of W^T, K-contiguous.
__device__ __forceinline__ void load_wfrag(const float* __restrict__ Wr,
                                           int w, int l15, int lq,
                                           short8 wf[2][4]) {
#pragma unroll
    for (int n = 0; n < 2; ++n) {
        int c = (w * 2 + n) * 16 + l15;
#pragma unroll
        for (int kk = 0; kk < 4; ++kk) {
            int kb = kk * 32 + lq * 8;
            short8 f;
#pragma unroll
            for (int j = 0; j < 8; ++j)
                f[j] = (short)f2bf(Wr[(size_t)(kb + j) * D_DIM + c]);
            wf[n][kk] = f;
        }
    }
}

// 64x128 (rows x k, bf16, XOR-swizzled) LDS tile  @  W(128x128) -> acc 64x128
__device__ __forceinline__ void mfma_tile(const unsigned short* xs,
                                          const short8 wf[2][4],
                                          int l15, int lq, f32x4 acc[4][2]) {
#pragma unroll
    for (int kk = 0; kk < 4; ++kk) {
        short8 a[4];
#pragma unroll
        for (int m = 0; m < 4; ++m) {
            int row = m * 16 + l15;
            unsigned byte = ((unsigned)(row * 256 + (kk * 32 + lq * 8) * 2))
                          ^ (((unsigned)(row & 7)) << 4);
            a[m] = *reinterpret_cast<const short8*>(
                       reinterpret_cast<const char*>(xs) + byte);
        }
#pragma unroll
        for (int m = 0; m < 4; ++m)
#pragma unroll
            for (int n = 0; n < 2; ++n)
                acc[m][n] = __builtin_amdgcn_mfma_f32_16x16x32_bf16(
                                a[m], wf[n][kk], acc[m][n], 0, 0, 0);
    }
}

// ---------------- self term: out[r] = x[r] @ W[0] + b[0]  (plain store) ----
__global__ __launch_bounds__(256) void self_kernel(const float* __restrict__ x,
                                                   const float* __restrict__ W,
                                                   const float* __restrict__ b,
                                                   float* __restrict__ out,
                                                   int cpb) {
    __shared__ unsigned short xs[64 * D_DIM];
    const int tid = threadIdx.x;
    const int lane = tid & 63, w = tid >> 6;
    const int l15 = lane & 15, lq = lane >> 4;

    short8 wf[2][4];
    load_wfrag(W, w, l15, lq, wf);
    float bias[2];
#pragma unroll
    for (int n = 0; n < 2; ++n) bias[n] = b[(w * 2 + n) * 16 + l15];

    for (int ch = 0; ch < cpb; ++ch) {
        const int rbase = (blockIdx.x * cpb + ch) * 64;
        // stage 64 consecutive rows -> bf16 swizzled LDS
#pragma unroll
        for (int it = 0; it < 8; ++it) {
            int flat = it * 256 + tid;
            int row = flat >> 5, f4 = flat & 31;
            float4 v = *reinterpret_cast<const float4*>(
                           x + (size_t)(rbase + row) * D_DIM + f4 * 4);
            unsigned lo = (unsigned)f2bf(v.x) | ((unsigned)f2bf(v.y) << 16);
            unsigned hi = (unsigned)f2bf(v.z) | ((unsigned)f2bf(v.w) << 16);
            unsigned byte = ((unsigned)(row * 256 + f4 * 8))
                          ^ (((unsigned)(row & 7)) << 4);
            *reinterpret_cast<uint2*>(reinterpret_cast<char*>(xs) + byte) =
                make_uint2(lo, hi);
        }
        __syncthreads();

        f32x4 acc[4][2];
#pragma unroll
        for (int m = 0; m < 4; ++m)
#pragma unroll
            for (int n = 0; n < 2; ++n) acc[m][n] = (f32x4){0.f, 0.f, 0.f, 0.f};
        mfma_tile(xs, wf, l15, lq, acc);

#pragma unroll
        for (int m = 0; m < 4; ++m)
#pragma unroll
            for (int reg = 0; reg < 4; ++reg) {
                int row = rbase + m * 16 + lq * 4 + reg;
#pragma unroll
                for (int n = 0; n < 2; ++n) {
                    int c = (w * 2 + n) * 16 + l15;
                    out[(size_t)row * D_DIM + c] = acc[m][n][reg] + bias[n];
                }
            }
        __syncthreads();
    }
}

// ---------------- edge messages: atomicAdd(out[dst], x[src] @ W[2+vr] + b) --
__global__ __launch_bounds__(256) void edge_kernel(const float* __restrict__ x,
                                                   const float* __restrict__ W,
                                                   const float* __restrict__ b,
                                                   const int* __restrict__ dep,
                                                   const int* __restrict__ gov,
                                                   float* __restrict__ out,
                                                   int eg, int blocksPerRel,
                                                   int cpb) {
    __shared__ unsigned short xs[64 * D_DIM];
    __shared__ int sidx[64];
    __shared__ int didx[64];

    const int tid = threadIdx.x;
    const int lane = tid & 63, w = tid >> 6;
    const int l15 = lane & 15, lq = lane >> 4;

    const int bid = blockIdx.x;
    const int vr = bid / blocksPerRel;        // 0..63 virtual relation
    const int blk = bid % blocksPerRel;
    const int r = vr & 31;
    const bool fwd = (vr < 32);
    const int* __restrict__ srcI = fwd ? gov : dep;
    const int* __restrict__ dstI = fwd ? dep : gov;

    short8 wf[2][4];
    load_wfrag(W + (size_t)(2 + vr) * D_DIM * D_DIM, w, l15, lq, wf);
    float bias[2];
#pragma unroll
    for (int n = 0; n < 2; ++n)
        bias[n] = b[(size_t)(2 + vr) * D_DIM + (w * 2 + n) * 16 + l15];

    for (int ch = 0; ch < cpb; ++ch) {
        const int ebase = r * eg + (blk * cpb + ch) * 64;
        if (tid < 64) sidx[tid] = srcI[ebase + tid];
        else if (tid < 128) didx[tid - 64] = dstI[ebase + tid - 64];
        __syncthreads();

        // gather 64 source rows -> bf16 swizzled LDS
#pragma unroll
        for (int it = 0; it < 8; ++it) {
            int flat = it * 256 + tid;
            int row = flat >> 5, f4 = flat & 31;
            float4 v = *reinterpret_cast<const float4*>(
                           x + (size_t)sidx[row] * D_DIM + f4 * 4);
            unsigned lo = (unsigned)f2bf(v.x) | ((unsigned)f2bf(v.y) << 16);
            unsigned hi = (unsigned)f2bf(v.z) | ((unsigned)f2bf(v.w) << 16);
            unsigned byte = ((unsigned)(row * 256 + f4 * 8))
                          ^ (((unsigned)(row & 7)) << 4);
            *reinterpret_cast<uint2*>(reinterpret_cast<char*>(xs) + byte) =
                make_uint2(lo, hi);
        }
        __syncthreads();

        f32x4 acc[4][2];
#pragma unroll
        for (int m = 0; m < 4; ++m)
#pragma unroll
            for (int n = 0; n < 2; ++n) acc[m][n] = (f32x4){0.f, 0.f, 0.f, 0.f};
        mfma_tile(xs, wf, l15, lq, acc);

        // scatter-add messages
#pragma unroll
        for (int m = 0; m < 4; ++m)
#pragma unroll
            for (int reg = 0; reg < 4; ++reg) {
                int erow = m * 16 + lq * 4 + reg;
                int dst = didx[erow];
#pragma unroll
                for (int n = 0; n < 2; ++n) {
                    int c = (w * 2 + n) * 16 + l15;
                    unsafeAtomicAdd(&out[(size_t)dst * D_DIM + c],
                                    acc[m][n][reg] + bias[n]);
                }
            }
        __syncthreads();
    }
}

// ---------------- final ReLU ----------------
__global__ void relu_kernel(float* __restrict__ o, int n4) {
    int i = blockIdx.x * blockDim.x + threadIdx.x;
    int stride = gridDim.x * blockDim.x;
    float4* p = reinterpret_cast<float4*>(o);
    for (; i < n4; i += stride) {
        float4 v = p[i];
        v.x = fmaxf(v.x, 0.f); v.y = fmaxf(v.y, 0.f);
        v.z = fmaxf(v.z, 0.f); v.w = fmaxf(v.w, 0.f);
        p[i] = v;
    }
}

extern "C" void kernel_launch(void* const* d_in, const int* in_sizes, int n_in,
                              void* d_out, int out_size, void* d_ws, size_t ws_size,
                              hipStream_t stream) {
    const float* x   = (const float*)d_in[0];
    const float* W   = (const float*)d_in[1];
    const float* b   = (const float*)d_in[2];
    const int*   dep = (const int*)d_in[3];
    const int*   gov = (const int*)d_in[4];
    float* out = (float*)d_out;

    const int N  = in_sizes[0] / D_DIM;   // 262144
    const int E  = in_sizes[3];           // 262144
    const int eg = E / L_REL;             // 8192

    // 1) self term (initializes out)
    const int selfCPB = 2;
    const int selfBlocks = (N / 64) / selfCPB;     // 2048
    self_kernel<<<selfBlocks, 256, 0, stream>>>(x, W, b, out, selfCPB);

    // 2) edge messages (atomic accumulate)
    const int blocksPerRel = 16;
    const int cpb = eg / 64 / blocksPerRel;        // 8 chunks of 64 edges
    edge_kernel<<<64 * blocksPerRel, 256, 0, stream>>>(x, W, b, dep, gov, out,
                                                       eg, blocksPerRel, cpb);

    // 3) ReLU
    const int n4 = out_size / 4;
    relu_kernel<<<2048, 256, 0, stream>>>(out, n4);
}

// Round 2
// 318.978 us; speedup vs baseline: 1.0316x; 1.0316x over previous
//
#include <hip/hip_runtime.h>
#include <hip/hip_bf16.h>
#include <stdint.h>

#define D_DIM 128
#define L_REL 32

typedef __attribute__((ext_vector_type(8))) short short8;   // 8 bf16 = 4 VGPR
typedef __attribute__((ext_vector_type(4))) float f32x4;    // MFMA accumulator

__device__ __forceinline__ unsigned short f2bf(float f) {
    union { float f; unsigned u; } v; v.f = f;
    unsigned r = v.u + 0x7FFFu + ((v.u >> 16) & 1u);   // round-to-nearest-even
    return (unsigned short)(r >> 16);
}

// Load W fragments for this wave's 32 output columns into registers.
// b-operand fragment: lane holds W[k][c] for c = tile*16 + (lane&15),
// k = kk*32 + (lane>>4)*8 + j  (j contiguous) -- i.e. rows of W^T, K-contiguous.
__device__ __forceinline__ void load_wfrag(const float* __restrict__ Wr,
                                           int w, int l15, int lq,
                                           short8 wf[2][4]) {
#pragma unroll
    for (int n = 0; n < 2; ++n) {
        int c = (w * 2 + n) * 16 + l15;
#pragma unroll
        for (int kk = 0; kk < 4; ++kk) {
            int kb = kk * 32 + lq * 8;
            short8 f;
#pragma unroll
            for (int j = 0; j < 8; ++j)
                f[j] = (short)f2bf(Wr[(size_t)(kb + j) * D_DIM + c]);
            wf[n][kk] = f;
        }
    }
}

// 64x128 (rows x k, bf16, XOR-swizzled) LDS tile  @  W(128x128) -> acc 64x128
__device__ __forceinline__ void mfma_tile(const unsigned short* xs,
                                          const short8 wf[2][4],
                                          int l15, int lq, f32x4 acc[4][2]) {
#pragma unroll
    for (int kk = 0; kk < 4; ++kk) {
        short8 a[4];
#pragma unroll
        for (int m = 0; m < 4; ++m) {
            int row = m * 16 + l15;
            unsigned byte = ((unsigned)(row * 256 + (kk * 32 + lq * 8) * 2))
                          ^ (((unsigned)(row & 7)) << 4);
            a[m] = *reinterpret_cast<const short8*>(
                       reinterpret_cast<const char*>(xs) + byte);
        }
#pragma unroll
        for (int m = 0; m < 4; ++m)
#pragma unroll
            for (int n = 0; n < 2; ++n)
                acc[m][n] = __builtin_amdgcn_mfma_f32_16x16x32_bf16(
                                a[m], wf[n][kk], acc[m][n], 0, 0, 0);
    }
}

// ---------------- self term: out[r] = x[r] @ W[0] + b[0]  (plain store) ----
__global__ __launch_bounds__(256) void self_kernel(const float* __restrict__ x,
                                                   const float* __restrict__ W,
                                                   const float* __restrict__ b,
                                                   float* __restrict__ out) {
    __shared__ unsigned short xs[64 * D_DIM];
    const int tid = threadIdx.x;
    const int lane = tid & 63, w = tid >> 6;
    const int l15 = lane & 15, lq = lane >> 4;

    short8 wf[2][4];
    load_wfrag(W, w, l15, lq, wf);
    float bias[2];
#pragma unroll
    for (int n = 0; n < 2; ++n) bias[n] = b[(w * 2 + n) * 16 + l15];

    const int rbase = blockIdx.x * 64;
    // stage 64 consecutive rows -> bf16 swizzled LDS
#pragma unroll
    for (int it = 0; it < 8; ++it) {
        int flat = it * 256 + tid;
        int row = flat >> 5, f4 = flat & 31;
        float4 v = *reinterpret_cast<const float4*>(
                       x + (size_t)(rbase + row) * D_DIM + f4 * 4);
        unsigned lo = (unsigned)f2bf(v.x) | ((unsigned)f2bf(v.y) << 16);
        unsigned hi = (unsigned)f2bf(v.z) | ((unsigned)f2bf(v.w) << 16);
        unsigned byte = ((unsigned)(row * 256 + f4 * 8))
                      ^ (((unsigned)(row & 7)) << 4);
        *reinterpret_cast<uint2*>(reinterpret_cast<char*>(xs) + byte) =
            make_uint2(lo, hi);
    }
    __syncthreads();

    f32x4 acc[4][2];
#pragma unroll
    for (int m = 0; m < 4; ++m)
#pragma unroll
        for (int n = 0; n < 2; ++n) acc[m][n] = (f32x4){0.f, 0.f, 0.f, 0.f};
    mfma_tile(xs, wf, l15, lq, acc);

#pragma unroll
    for (int m = 0; m < 4; ++m)
#pragma unroll
        for (int reg = 0; reg < 4; ++reg) {
            int row = rbase + m * 16 + lq * 4 + reg;
#pragma unroll
            for (int n = 0; n < 2; ++n) {
                int c = (w * 2 + n) * 16 + l15;
                out[(size_t)row * D_DIM + c] = acc[m][n][reg] + bias[n];
            }
        }
}

// ---------------- edge messages: atomicAdd(out[dst], x[src] @ W[2+vr] + b) --
#define CPB 2
__global__ __launch_bounds__(256) void edge_kernel(const float* __restrict__ x,
                                                   const float* __restrict__ W,
                                                   const float* __restrict__ b,
                                                   const int* __restrict__ dep,
                                                   const int* __restrict__ gov,
                                                   float* __restrict__ out,
                                                   int eg, int blocksPerRel) {
    __shared__ unsigned short xs[64 * D_DIM];
    __shared__ int sidx[CPB][64];
    __shared__ int didx[CPB][64];

    const int tid = threadIdx.x;
    const int lane = tid & 63, w = tid >> 6;
    const int l15 = lane & 15, lq = lane >> 4;

    const int bid = blockIdx.x;
    const int vr = bid / blocksPerRel;        // 0..63 virtual relation
    const int blk = bid % blocksPerRel;
    const int r = vr & 31;
    const bool fwd = (vr < 32);
    const int* __restrict__ srcI = fwd ? gov : dep;
    const int* __restrict__ dstI = fwd ? dep : gov;

    // preload all chunk indices for this block
    const int ebase0 = r * eg + blk * CPB * 64;
    if (tid < CPB * 64) {
        int c = tid >> 6, t = tid & 63;
        sidx[c][t] = srcI[ebase0 + c * 64 + t];
        didx[c][t] = dstI[ebase0 + c * 64 + t];
    }

    short8 wf[2][4];
    load_wfrag(W + (size_t)(2 + vr) * D_DIM * D_DIM, w, l15, lq, wf);
    float bias[2];
#pragma unroll
    for (int n = 0; n < 2; ++n)
        bias[n] = b[(size_t)(2 + vr) * D_DIM + (w * 2 + n) * 16 + l15];

    __syncthreads();

#pragma unroll
    for (int ch = 0; ch < CPB; ++ch) {
        // gather 64 source rows -> bf16 swizzled LDS
#pragma unroll
        for (int it = 0; it < 8; ++it) {
            int flat = it * 256 + tid;
            int row = flat >> 5, f4 = flat & 31;
            float4 v = *reinterpret_cast<const float4*>(
                           x + (size_t)sidx[ch][row] * D_DIM + f4 * 4);
            unsigned lo = (unsigned)f2bf(v.x) | ((unsigned)f2bf(v.y) << 16);
            unsigned hi = (unsigned)f2bf(v.z) | ((unsigned)f2bf(v.w) << 16);
            unsigned byte = ((unsigned)(row * 256 + f4 * 8))
                          ^ (((unsigned)(row & 7)) << 4);
            *reinterpret_cast<uint2*>(reinterpret_cast<char*>(xs) + byte) =
                make_uint2(lo, hi);
        }
        __syncthreads();

        f32x4 acc[4][2];
#pragma unroll
        for (int m = 0; m < 4; ++m)
#pragma unroll
            for (int n = 0; n < 2; ++n) acc[m][n] = (f32x4){0.f, 0.f, 0.f, 0.f};
        mfma_tile(xs, wf, l15, lq, acc);

        // scatter-add messages
#pragma unroll
        for (int m = 0; m < 4; ++m)
#pragma unroll
            for (int reg = 0; reg < 4; ++reg) {
                int erow = m * 16 + lq * 4 + reg;
                int dst = didx[ch][erow];
#pragma unroll
                for (int n = 0; n < 2; ++n) {
                    int c = (w * 2 + n) * 16 + l15;
                    unsafeAtomicAdd(&out[(size_t)dst * D_DIM + c],
                                    acc[m][n][reg] + bias[n]);
                }
            }
        __syncthreads();
    }
}

// ---------------- final ReLU ----------------
__global__ void relu_kernel(float* __restrict__ o, int n4) {
    int i = blockIdx.x * blockDim.x + threadIdx.x;
    int stride = gridDim.x * blockDim.x;
    float4* p = reinterpret_cast<float4*>(o);
    for (; i < n4; i += stride) {
        float4 v = p[i];
        v.x = fmaxf(v.x, 0.f); v.y = fmaxf(v.y, 0.f);
        v.z = fmaxf(v.z, 0.f); v.w = fmaxf(v.w, 0.f);
        p[i] = v;
    }
}

extern "C" void kernel_launch(void* const* d_in, const int* in_sizes, int n_in,
                              void* d_out, int out_size, void* d_ws, size_t ws_size,
                              hipStream_t stream) {
    const float* x   = (const float*)d_in[0];
    const float* W   = (const float*)d_in[1];
    const float* b   = (const float*)d_in[2];
    const int*   dep = (const int*)d_in[3];
    const int*   gov = (const int*)d_in[4];
    float* out = (float*)d_out;

    const int N  = in_sizes[0] / D_DIM;   // 262144
    const int E  = in_sizes[3];           // 262144
    const int eg = E / L_REL;             // 8192

    // 1) self term (initializes out)
    const int selfBlocks = N / 64;                 // 4096
    self_kernel<<<selfBlocks, 256, 0, stream>>>(x, W, b, out);

    // 2) edge messages (atomic accumulate) -- 64 vrel x 64 blocks = 4096 blocks
    const int blocksPerRel = eg / 64 / CPB;        // 64
    edge_kernel<<<64 * blocksPerRel, 256, 0, stream>>>(x, W, b, dep, gov, out,
                                                       eg, blocksPerRel);

    // 3) ReLU
    const int n4 = out_size / 4;
    relu_kernel<<<2048, 256, 0, stream>>>(out, n4);
}

// Round 3
// 291.900 us; speedup vs baseline: 1.1273x; 1.0928x over previous
//
#include <hip/hip_runtime.h>
#include <hip/hip_bf16.h>
#include <stdint.h>

#define D_DIM 128
#define L_REL 32
#define AGG_LDW 132   // padded f32 row stride (dwords) to break LDS bank conflicts

typedef __attribute__((ext_vector_type(8))) short short8;   // 8 bf16 = 4 VGPR
typedef __attribute__((ext_vector_type(4))) float f32x4;    // MFMA accumulator

__device__ __forceinline__ unsigned short f2bf(float f) {
    union { float f; unsigned u; } v; v.f = f;
    unsigned r = v.u + 0x7FFFu + ((v.u >> 16) & 1u);   // round-to-nearest-even
    return (unsigned short)(r >> 16);
}
__device__ __forceinline__ float bf_lo(unsigned m) { return __uint_as_float(m << 16); }
__device__ __forceinline__ float bf_hi(unsigned m) { return __uint_as_float(m & 0xffff0000u); }

// B-operand fragment: lane holds W[k][c] for c = tile*16 + (lane&15),
// k = kk*32 + (lane>>4)*8 + j (j contiguous).
__device__ __forceinline__ void load_wfrag(const float* __restrict__ Wr,
                                           int w, int l15, int lq,
                                           short8 wf[2][4]) {
#pragma unroll
    for (int n = 0; n < 2; ++n) {
        int c = (w * 2 + n) * 16 + l15;
#pragma unroll
        for (int kk = 0; kk < 4; ++kk) {
            int kb = kk * 32 + lq * 8;
            short8 f;
#pragma unroll
            for (int j = 0; j < 8; ++j)
                f[j] = (short)f2bf(Wr[(size_t)(kb + j) * D_DIM + c]);
            wf[n][kk] = f;
        }
    }
}

// 64x128 (rows x k, bf16, XOR-swizzled) LDS tile  @  W(128x128) -> acc 64x128
__device__ __forceinline__ void mfma_tile(const unsigned short* xs,
                                          const short8 wf[2][4],
                                          int l15, int lq, f32x4 acc[4][2]) {
#pragma unroll
    for (int kk = 0; kk < 4; ++kk) {
        short8 a[4];
#pragma unroll
        for (int m = 0; m < 4; ++m) {
            int row = m * 16 + l15;
            unsigned byte = ((unsigned)(row * 256 + (kk * 32 + lq * 8) * 2))
                          ^ (((unsigned)(row & 7)) << 4);
            a[m] = *reinterpret_cast<const short8*>(
                       reinterpret_cast<const char*>(xs) + byte);
        }
#pragma unroll
        for (int m = 0; m < 4; ++m)
#pragma unroll
            for (int n = 0; n < 2; ++n)
                acc[m][n] = __builtin_amdgcn_mfma_f32_16x16x32_bf16(
                                a[m], wf[n][kk], acc[m][n], 0, 0, 0);
    }
}

// ============================ CSR build chain ==============================
__global__ void hist_kernel(const int* __restrict__ dep, const int* __restrict__ gov,
                            int* __restrict__ degF, int* __restrict__ degR, int E) {
    int i = blockIdx.x * blockDim.x + threadIdx.x;
    int stride = gridDim.x * blockDim.x;
    for (; i < E; i += stride) {
        atomicAdd(&degF[dep[i]], 1);
        atomicAdd(&degR[gov[i]], 1);
    }
}

// per-block exclusive scan of 1024 ints (256 thr x int4); block totals -> partials
__global__ __launch_bounds__(256) void scanA_kernel(const int* __restrict__ deg,
                                                    int* __restrict__ off,
                                                    int* __restrict__ partials, int N) {
    __shared__ int ls[256];
    const int dir = blockIdx.y;
    const int tid = threadIdx.x;
    const int4* in4 = (const int4*)(deg + (size_t)dir * N);
    int4* out4 = (int4*)(off + (size_t)dir * N);
    const int gi = blockIdx.x * 256 + tid;
    int4 v = in4[gi];
    int s = v.x + v.y + v.z + v.w;
    ls[tid] = s;
    __syncthreads();
    for (int o = 1; o < 256; o <<= 1) {
        int t = (tid >= o) ? ls[tid - o] : 0;
        __syncthreads();
        ls[tid] += t;
        __syncthreads();
    }
    int e0 = ls[tid] - s;
    int4 e; e.x = e0; e.y = e0 + v.x; e.z = e.y + v.y; e.w = e.z + v.z;
    out4[gi] = e;
    if (tid == 255) partials[dir * 256 + blockIdx.x] = ls[255];
}

__global__ __launch_bounds__(256) void scanB_kernel(int* __restrict__ partials) {
    __shared__ int ls[256];
    const int dir = blockIdx.x;
    const int tid = threadIdx.x;
    int v = partials[dir * 256 + tid];
    ls[tid] = v;
    __syncthreads();
    for (int o = 1; o < 256; o <<= 1) {
        int t = (tid >= o) ? ls[tid - o] : 0;
        __syncthreads();
        ls[tid] += t;
        __syncthreads();
    }
    partials[dir * 256 + tid] = ls[tid] - v;   // exclusive
}

__global__ __launch_bounds__(256) void scanC_kernel(int* __restrict__ off,
                                                    int* __restrict__ cur,
                                                    const int* __restrict__ partials, int N) {
    const int dir = blockIdx.y;
    const int p = partials[dir * 256 + blockIdx.x];
    const int gi = blockIdx.x * 256 + threadIdx.x;
    int4* o4 = (int4*)(off + (size_t)dir * N);
    int4* c4 = (int4*)(cur + (size_t)dir * N);
    int4 v = o4[gi];
    v.x += p; v.y += p; v.z += p; v.w += p;
    o4[gi] = v;
    c4[gi] = v;
}

// ====================== messages -> dst-sorted bf16 buffer ==================
#define CPB 2
__global__ __launch_bounds__(256) void msg_kernel(const float* __restrict__ x,
                                                  const float* __restrict__ W,
                                                  const float* __restrict__ b,
                                                  const int* __restrict__ dep,
                                                  const int* __restrict__ gov,
                                                  int* __restrict__ cur,
                                                  unsigned* __restrict__ msgF,
                                                  unsigned* __restrict__ msgR,
                                                  int eg, int blocksPerRel, int N) {
    __shared__ __align__(16) char smem[64 * AGG_LDW * 4];   // xs (16KB) then agg f32
    unsigned short* xs = (unsigned short*)smem;
    float* agg = (float*)smem;
    __shared__ int sidx[CPB][64];
    __shared__ int didx[CPB][64];
    __shared__ int pos[64];

    const int tid = threadIdx.x;
    const int lane = tid & 63, w = tid >> 6;
    const int l15 = lane & 15, lq = lane >> 4;

    const int bid = blockIdx.x;
    const int vr = bid / blocksPerRel;
    const int blk = bid % blocksPerRel;
    const int r = vr & 31;
    const bool fwd = (vr < 32);
    const int* __restrict__ srcI = fwd ? gov : dep;
    const int* __restrict__ dstI = fwd ? dep : gov;
    int* curD = cur + (fwd ? 0 : N);
    unsigned* msgD = fwd ? msgF : msgR;

    const int ebase0 = r * eg + blk * CPB * 64;
    if (tid < CPB * 64) {
        int c = tid >> 6, t = tid & 63;
        sidx[c][t] = srcI[ebase0 + c * 64 + t];
        didx[c][t] = dstI[ebase0 + c * 64 + t];
    }

    short8 wf[2][4];
    load_wfrag(W + (size_t)(2 + vr) * D_DIM * D_DIM, w, l15, lq, wf);
    float bias[2];
#pragma unroll
    for (int n = 0; n < 2; ++n)
        bias[n] = b[(size_t)(2 + vr) * D_DIM + (w * 2 + n) * 16 + l15];

    __syncthreads();

    for (int ch = 0; ch < CPB; ++ch) {
        // gather 64 source rows -> bf16 swizzled LDS
#pragma unroll
        for (int it = 0; it < 8; ++it) {
            int flat = it * 256 + tid;
            int row = flat >> 5, f4 = flat & 31;
            float4 v = *reinterpret_cast<const float4*>(
                           x + (size_t)sidx[ch][row] * D_DIM + f4 * 4);
            unsigned lo = (unsigned)f2bf(v.x) | ((unsigned)f2bf(v.y) << 16);
            unsigned hi = (unsigned)f2bf(v.z) | ((unsigned)f2bf(v.w) << 16);
            unsigned byte = ((unsigned)(row * 256 + f4 * 8))
                          ^ (((unsigned)(row & 7)) << 4);
            *reinterpret_cast<uint2*>(reinterpret_cast<char*>(xs) + byte) =
                make_uint2(lo, hi);
        }
        __syncthreads();

        f32x4 acc[4][2];
#pragma unroll
        for (int m = 0; m < 4; ++m)
#pragma unroll
            for (int n = 0; n < 2; ++n) acc[m][n] = (f32x4){0.f, 0.f, 0.f, 0.f};
        mfma_tile(xs, wf, l15, lq, acc);

        // reserve dst-sorted slots: ONE int atomic per edge
        if (tid < 64) pos[tid] = atomicAdd(&curD[didx[ch][tid]], 1);
        __syncthreads();   // xs reads done; pos visible

        // transpose acc (+bias) through LDS f32 [64][AGG_LDW]
#pragma unroll
        for (int m = 0; m < 4; ++m)
#pragma unroll
            for (int reg = 0; reg < 4; ++reg) {
                int row = m * 16 + lq * 4 + reg;
#pragma unroll
                for (int n = 0; n < 2; ++n)
                    agg[row * AGG_LDW + w * 32 + n * 16 + l15] =
                        acc[m][n][reg] + bias[n];
            }
        __syncthreads();

        // wave-per-row: pack bf16 pairs, store 256B contiguous at sorted slot
#pragma unroll
        for (int i = 0; i < 16; ++i) {
            int r0 = w * 16 + i;
            float2 v = *reinterpret_cast<const float2*>(&agg[r0 * AGG_LDW + lane * 2]);
            unsigned dw = (unsigned)f2bf(v.x) | ((unsigned)f2bf(v.y) << 16);
            msgD[(size_t)pos[r0] * 64 + lane] = dw;
        }
        __syncthreads();
    }
}

// ============== fused: self-GEMM + gather-aggregate + bias + ReLU ==========
__global__ __launch_bounds__(256) void agg_kernel(const float* __restrict__ x,
                                                  const float* __restrict__ W,
                                                  const float* __restrict__ b,
                                                  const int* __restrict__ off,
                                                  const int* __restrict__ deg,
                                                  const unsigned* __restrict__ msgF,
                                                  const unsigned* __restrict__ msgR,
                                                  float* __restrict__ out, int N) {
    __shared__ __align__(16) char smem[64 * AGG_LDW * 4];
    unsigned short* xs = (unsigned short*)smem;
    float* agg = (float*)smem;
    __shared__ int offF[64], degF[64], offR[64], degR[64];

    const int tid = threadIdx.x;
    const int lane = tid & 63, w = tid >> 6;
    const int l15 = lane & 15, lq = lane >> 4;
    const int base = blockIdx.x * 64;

    if (tid < 64) offF[tid] = off[base + tid];
    else if (tid < 128) degF[tid - 64] = deg[base + tid - 64];
    else if (tid < 192) offR[tid - 128] = off[(size_t)N + base + tid - 128];
    else degR[tid - 192] = deg[(size_t)N + base + tid - 192];

    short8 wf[2][4];
    load_wfrag(W, w, l15, lq, wf);          // W[SELF]
    float bias[2];
#pragma unroll
    for (int n = 0; n < 2; ++n) bias[n] = b[(w * 2 + n) * 16 + l15];

    // stage 64 consecutive node rows
#pragma unroll
    for (int it = 0; it < 8; ++it) {
        int flat = it * 256 + tid;
        int row = flat >> 5, f4 = flat & 31;
        float4 v = *reinterpret_cast<const float4*>(
                       x + (size_t)(base + row) * D_DIM + f4 * 4);
        unsigned lo = (unsigned)f2bf(v.x) | ((unsigned)f2bf(v.y) << 16);
        unsigned hi = (unsigned)f2bf(v.z) | ((unsigned)f2bf(v.w) << 16);
        unsigned byte = ((unsigned)(row * 256 + f4 * 8))
                      ^ (((unsigned)(row & 7)) << 4);
        *reinterpret_cast<uint2*>(reinterpret_cast<char*>(xs) + byte) =
            make_uint2(lo, hi);
    }
    __syncthreads();

    f32x4 acc[4][2];
#pragma unroll
    for (int m = 0; m < 4; ++m)
#pragma unroll
        for (int n = 0; n < 2; ++n) acc[m][n] = (f32x4){0.f, 0.f, 0.f, 0.f};
    mfma_tile(xs, wf, l15, lq, acc);
    __syncthreads();   // xs consumed; reuse LDS as f32 agg

    // self-term (+bias) -> LDS transpose
#pragma unroll
    for (int m = 0; m < 4; ++m)
#pragma unroll
        for (int reg = 0; reg < 4; ++reg) {
            int row = m * 16 + lq * 4 + reg;
#pragma unroll
            for (int n = 0; n < 2; ++n)
                agg[row * AGG_LDW + w * 32 + n * 16 + l15] =
                    acc[m][n][reg] + bias[n];
        }
    __syncthreads();

    // wave-per-node: self + sum(fwd msgs) + sum(rev msgs), ReLU, store
#pragma unroll 1
    for (int i = 0; i < 16; ++i) {
        int nl = w * 16 + i;
        float2 s = *reinterpret_cast<const float2*>(&agg[nl * AGG_LDW + lane * 2]);
        {
            int o = offF[nl], d = degF[nl];
            const unsigned* p = msgF + (size_t)o * 64 + lane;
            for (int k = 0; k < d; ++k) {
                unsigned m = p[(size_t)k * 64];
                s.x += bf_lo(m); s.y += bf_hi(m);
            }
        }
        {
            int o = offR[nl], d = degR[nl];
            const unsigned* p = msgR + (size_t)o * 64 + lane;
            for (int k = 0; k < d; ++k) {
                unsigned m = p[(size_t)k * 64];
                s.x += bf_lo(m); s.y += bf_hi(m);
            }
        }
        s.x = fmaxf(s.x, 0.f); s.y = fmaxf(s.y, 0.f);
        *reinterpret_cast<float2*>(out + (size_t)(base + nl) * D_DIM + lane * 2) = s;
    }
}

// ===================== fallback (R2 atomic path) ===========================
__global__ __launch_bounds__(256) void self_kernel(const float* __restrict__ x,
                                                   const float* __restrict__ W,
                                                   const float* __restrict__ b,
                                                   float* __restrict__ out) {
    __shared__ unsigned short xs[64 * D_DIM];
    const int tid = threadIdx.x;
    const int lane = tid & 63, w = tid >> 6;
    const int l15 = lane & 15, lq = lane >> 4;
    short8 wf[2][4];
    load_wfrag(W, w, l15, lq, wf);
    float bias[2];
#pragma unroll
    for (int n = 0; n < 2; ++n) bias[n] = b[(w * 2 + n) * 16 + l15];
    const int rbase = blockIdx.x * 64;
#pragma unroll
    for (int it = 0; it < 8; ++it) {
        int flat = it * 256 + tid;
        int row = flat >> 5, f4 = flat & 31;
        float4 v = *reinterpret_cast<const float4*>(
                       x + (size_t)(rbase + row) * D_DIM + f4 * 4);
        unsigned lo = (unsigned)f2bf(v.x) | ((unsigned)f2bf(v.y) << 16);
        unsigned hi = (unsigned)f2bf(v.z) | ((unsigned)f2bf(v.w) << 16);
        unsigned byte = ((unsigned)(row * 256 + f4 * 8))
                      ^ (((unsigned)(row & 7)) << 4);
        *reinterpret_cast<uint2*>(reinterpret_cast<char*>(xs) + byte) =
            make_uint2(lo, hi);
    }
    __syncthreads();
    f32x4 acc[4][2];
#pragma unroll
    for (int m = 0; m < 4; ++m)
#pragma unroll
        for (int n = 0; n < 2; ++n) acc[m][n] = (f32x4){0.f, 0.f, 0.f, 0.f};
    mfma_tile(xs, wf, l15, lq, acc);
#pragma unroll
    for (int m = 0; m < 4; ++m)
#pragma unroll
        for (int reg = 0; reg < 4; ++reg) {
            int row = rbase + m * 16 + lq * 4 + reg;
#pragma unroll
            for (int n = 0; n < 2; ++n) {
                int c = (w * 2 + n) * 16 + l15;
                out[(size_t)row * D_DIM + c] = acc[m][n][reg] + bias[n];
            }
        }
}

__global__ __launch_bounds__(256) void edge_kernel(const float* __restrict__ x,
                                                   const float* __restrict__ W,
                                                   const float* __restrict__ b,
                                                   const int* __restrict__ dep,
                                                   const int* __restrict__ gov,
                                                   float* __restrict__ out,
                                                   int eg, int blocksPerRel) {
    __shared__ unsigned short xs[64 * D_DIM];
    __shared__ int sidx[CPB][64];
    __shared__ int didx[CPB][64];
    const int tid = threadIdx.x;
    const int lane = tid & 63, w = tid >> 6;
    const int l15 = lane & 15, lq = lane >> 4;
    const int bid = blockIdx.x;
    const int vr = bid / blocksPerRel;
    const int blk = bid % blocksPerRel;
    const int r = vr & 31;
    const bool fwd = (vr < 32);
    const int* __restrict__ srcI = fwd ? gov : dep;
    const int* __restrict__ dstI = fwd ? dep : gov;
    const int ebase0 = r * eg + blk * CPB * 64;
    if (tid < CPB * 64) {
        int c = tid >> 6, t = tid & 63;
        sidx[c][t] = srcI[ebase0 + c * 64 + t];
        didx[c][t] = dstI[ebase0 + c * 64 + t];
    }
    short8 wf[2][4];
    load_wfrag(W + (size_t)(2 + vr) * D_DIM * D_DIM, w, l15, lq, wf);
    float bias[2];
#pragma unroll
    for (int n = 0; n < 2; ++n)
        bias[n] = b[(size_t)(2 + vr) * D_DIM + (w * 2 + n) * 16 + l15];
    __syncthreads();
#pragma unroll
    for (int ch = 0; ch < CPB; ++ch) {
#pragma unroll
        for (int it = 0; it < 8; ++it) {
            int flat = it * 256 + tid;
            int row = flat >> 5, f4 = flat & 31;
            float4 v = *reinterpret_cast<const float4*>(
                           x + (size_t)sidx[ch][row] * D_DIM + f4 * 4);
            unsigned lo = (unsigned)f2bf(v.x) | ((unsigned)f2bf(v.y) << 16);
            unsigned hi = (unsigned)f2bf(v.z) | ((unsigned)f2bf(v.w) << 16);
            unsigned byte = ((unsigned)(row * 256 + f4 * 8))
                          ^ (((unsigned)(row & 7)) << 4);
            *reinterpret_cast<uint2*>(reinterpret_cast<char*>(xs) + byte) =
                make_uint2(lo, hi);
        }
        __syncthreads();
        f32x4 acc[4][2];
#pragma unroll
        for (int m = 0; m < 4; ++m)
#pragma unroll
            for (int n = 0; n < 2; ++n) acc[m][n] = (f32x4){0.f, 0.f, 0.f, 0.f};
        mfma_tile(xs, wf, l15, lq, acc);
#pragma unroll
        for (int m = 0; m < 4; ++m)
#pragma unroll
            for (int reg = 0; reg < 4; ++reg) {
                int erow = m * 16 + lq * 4 + reg;
                int dst = didx[ch][erow];
#pragma unroll
                for (int n = 0; n < 2; ++n) {
                    int c = (w * 2 + n) * 16 + l15;
                    unsafeAtomicAdd(&out[(size_t)dst * D_DIM + c],
                                    acc[m][n][reg] + bias[n]);
                }
            }
        __syncthreads();
    }
}

__global__ void relu_kernel(float* __restrict__ o, int n4) {
    int i = blockIdx.x * blockDim.x + threadIdx.x;
    int stride = gridDim.x * blockDim.x;
    float4* p = reinterpret_cast<float4*>(o);
    for (; i < n4; i += stride) {
        float4 v = p[i];
        v.x = fmaxf(v.x, 0.f); v.y = fmaxf(v.y, 0.f);
        v.z = fmaxf(v.z, 0.f); v.w = fmaxf(v.w, 0.f);
        p[i] = v;
    }
}

// ===========================================================================
extern "C" void kernel_launch(void* const* d_in, const int* in_sizes, int n_in,
                              void* d_out, int out_size, void* d_ws, size_t ws_size,
                              hipStream_t stream) {
    const float* x   = (const float*)d_in[0];
    const float* W   = (const float*)d_in[1];
    const float* b   = (const float*)d_in[2];
    const int*   dep = (const int*)d_in[3];
    const int*   gov = (const int*)d_in[4];
    float* out = (float*)d_out;

    const int N  = in_sizes[0] / D_DIM;   // 262144
    const int E  = in_sizes[3];           // 262144
    const int eg = E / L_REL;             // 8192

    const size_t msgBytes = (size_t)E * 64 * sizeof(unsigned);   // 67.1 MB per dir
    const size_t csrInts  = (size_t)6 * N;                       // deg/off/cur x2
    const size_t need = 2 * msgBytes + csrInts * 4 + 4096;

    if (ws_size >= need) {
        char* base = (char*)d_ws;
        unsigned* msgF = (unsigned*)base;
        unsigned* msgR = (unsigned*)(base + msgBytes);
        int* deg = (int*)(base + 2 * msgBytes);   // [2][N]
        int* off = deg + 2 * (size_t)N;           // [2][N]
        int* cur = off + 2 * (size_t)N;           // [2][N]
        int* partials = cur + 2 * (size_t)N;      // [2][256]

        hipMemsetAsync(deg, 0, (size_t)2 * N * sizeof(int), stream);
        hist_kernel<<<512, 256, 0, stream>>>(dep, gov, deg, deg + N, E);
        scanA_kernel<<<dim3(N / 1024, 2), 256, 0, stream>>>(deg, off, partials, N);
        scanB_kernel<<<2, 256, 0, stream>>>(partials);
        scanC_kernel<<<dim3(N / 1024, 2), 256, 0, stream>>>(off, cur, partials, N);

        const int blocksPerRel = eg / 64 / CPB;   // 64
        msg_kernel<<<64 * blocksPerRel, 256, 0, stream>>>(x, W, b, dep, gov, cur,
                                                          msgF, msgR, eg,
                                                          blocksPerRel, N);
        agg_kernel<<<N / 64, 256, 0, stream>>>(x, W, b, off, deg, msgF, msgR,
                                               out, N);
    } else {
        // fallback: atomic scatter path
        self_kernel<<<N / 64, 256, 0, stream>>>(x, W, b, out);
        const int blocksPerRel = eg / 64 / CPB;
        edge_kernel<<<64 * blocksPerRel, 256, 0, stream>>>(x, W, b, dep, gov, out,
                                                           eg, blocksPerRel);
        relu_kernel<<<2048, 256, 0, stream>>>(out, out_size / 4);
    }
}